// Round 1
// baseline (379.172 us; speedup 1.0000x reference)
//
#include <hip/hip_runtime.h>
#include <stdint.h>

// QuantumGeometricAttention — algebraically refactored:
//   G = Wm Wm^H (64x64 cplx)  folded into Wq  (-> scores inner dim 128 real)
//   H = Wm Wmi  (64x64 cplx)  folded into Wo  (-> PV inner dim 128 real)
// Pipeline: norm -> fold weights -> QKV GEMM (bf16 MFMA) -> flash attn -> out GEMM.
// B=2, S=2048, HIDDEN=512, HEADS=8, HEAD_DIM=64. TOK=4096.
// ws layout (bytes):
//   0        xn     bf16 [4096][512]    4 MB
//   4 MB     WqkvT  bf16 [3072][512]    3 MB   (B^T for QKV gemm, Q part has G+scale folded)
//   7 MB     Wbig   bf16 [1024][1024]   2 MB   (B^T for out gemm, H folded, re/im col-interleaved)
//   9 MB     GH     f32  [4][64][64]    64 KB  (G_re,G_im,H_re,H_im)
//   10 MB    QK     bf16 [4096][2048]   16 MB  (cols 0..1023 = Qtilde, 1024..2047 = K)
//   26 MB    Vt     bf16 [16][128][2048] 8 MB  (V transposed, d-major per (b,h))
//   34 MB    Obuf   bf16 [4096][1024]   8 MB
// total 42 MB

typedef __attribute__((ext_vector_type(8))) short bf16x8;
typedef __attribute__((ext_vector_type(4))) float f32x4;

#define QSCALE 0.18033688011112042f  /* 64^-0.5 * log2(e) */

__device__ __forceinline__ unsigned short f2b(float f) {
    union { float f; unsigned int u; } v; v.f = f;
    unsigned int r = v.u + 0x7fffu + ((v.u >> 16) & 1u);  // RNE
    return (unsigned short)(r >> 16);
}

// ---------------- 1. row L2-normalize + bf16 cast: 1 wave per token ----------------
__global__ __launch_bounds__(256) void k_norm(const float* __restrict__ x,
                                              unsigned short* __restrict__ xn) {
    int row  = blockIdx.x * 4 + (threadIdx.x >> 6);
    int lane = threadIdx.x & 63;
    const float4* xr = (const float4*)(x + (size_t)row * 512);
    float4 a = xr[lane], b = xr[lane + 64];
    float s = a.x*a.x + a.y*a.y + a.z*a.z + a.w*a.w
            + b.x*b.x + b.y*b.y + b.z*b.z + b.w*b.w;
    #pragma unroll
    for (int m = 1; m < 64; m <<= 1) s += __shfl_xor(s, m, 64);
    float inv = 1.0f / sqrtf(s);
    ushort4 o;
    o.x = f2b(a.x*inv); o.y = f2b(a.y*inv); o.z = f2b(a.z*inv); o.w = f2b(a.w*inv);
    *(ushort4*)&xn[(size_t)row*512 + lane*4] = o;
    o.x = f2b(b.x*inv); o.y = f2b(b.y*inv); o.z = f2b(b.z*inv); o.w = f2b(b.w*inv);
    *(ushort4*)&xn[(size_t)row*512 + 256 + lane*4] = o;
}

// ---------------- 2. G = Wm Wm^H, H = Wm Wmi (fp32) ----------------
__global__ __launch_bounds__(256) void k_gh(const float* __restrict__ Wm_re, const float* __restrict__ Wm_im,
                                            const float* __restrict__ Wmi_re, const float* __restrict__ Wmi_im,
                                            float* __restrict__ GH) {
    int id = blockIdx.x * 256 + threadIdx.x;   // 16384
    int mat = id >> 12;
    int a = (id >> 6) & 63, c = id & 63;
    float s = 0.f;
    if (mat < 2) {
        for (int m = 0; m < 256; m++) {
            float ar = Wm_re[a*256+m], ai = Wm_im[a*256+m];
            float br = Wm_re[c*256+m], bi = Wm_im[c*256+m];
            s += (mat == 0) ? (ar*br + ai*bi) : (ai*br - ar*bi);   // G = Wm conj(Wm)^T
        }
    } else {
        for (int m = 0; m < 256; m++) {
            float ar = Wm_re[a*256+m], ai = Wm_im[a*256+m];
            float br = Wmi_re[m*64+c], bi = Wmi_im[m*64+c];
            s += (mat == 2) ? (ar*br - ai*bi) : (ar*bi + ai*br);   // H = Wm Wmi
        }
    }
    GH[id] = s;
}

// ---------------- 3. pack WqkvT [3072 n][512 k] bf16 ----------------
// n<1024: Qtilde cols (h,part,j): (Wq_head @ G) * QSCALE ; 1024..2047: K ; 2048..: V
__global__ __launch_bounds__(256) void k_packqkv(
        const float* __restrict__ Wq_re, const float* __restrict__ Wq_im,
        const float* __restrict__ Wk_re, const float* __restrict__ Wk_im,
        const float* __restrict__ Wv_re, const float* __restrict__ Wv_im,
        const float* __restrict__ GH, unsigned short* __restrict__ WqkvT) {
    int id = blockIdx.x * 256 + threadIdx.x;  // 3072*512
    int n = id >> 9, k = id & 511;
    float val;
    if (n < 1024) {
        int h = n >> 7, part = (n >> 6) & 1, j = n & 63;
        const float* Gr = GH;
        const float* Gi = GH + 4096;
        const float* qr = Wq_re + (size_t)k*512 + h*64;
        const float* qi = Wq_im + (size_t)k*512 + h*64;
        float s = 0.f;
        if (part == 0) { for (int d = 0; d < 64; d++) s += qr[d]*Gr[d*64+j] - qi[d]*Gi[d*64+j]; }
        else           { for (int d = 0; d < 64; d++) s += qr[d]*Gi[d*64+j] + qi[d]*Gr[d*64+j]; }
        val = s * QSCALE;
    } else if (n < 2048) {
        int m = n - 1024; int h = m >> 7, part = (m >> 6) & 1, j = m & 63;
        val = (part ? Wk_im : Wk_re)[(size_t)k*512 + h*64 + j];
    } else {
        int m = n - 2048; int h = m >> 7, part = (m >> 6) & 1, j = m & 63;
        val = (part ? Wv_im : Wv_re)[(size_t)k*512 + h*64 + j];
    }
    WqkvT[id] = f2b(val);
}

// ---------------- 4. pack Wbig [1024 n'][1024 kk] bf16 ----------------
// n' = 2c+p (p: 0=re,1=im of out col c). kk = 128h + 64pp + d (pp: O re/im half).
// Wo'[64h+d][c] = sum_j H[d][j] Wo[64h+j][c]  (complex)
__global__ __launch_bounds__(256) void k_packwo(
        const float* __restrict__ Wo_re, const float* __restrict__ Wo_im,
        const float* __restrict__ GH, unsigned short* __restrict__ Wbig) {
    int id = blockIdx.x * 256 + threadIdx.x;  // 1024*1024
    int np = id >> 10, kk = id & 1023;
    int c = np >> 1, p = np & 1;
    int h = kk >> 7, pp = (kk >> 6) & 1, d = kk & 63;
    const float* Hr = GH + 2*4096;
    const float* Hi = GH + 3*4096;
    float s = 0.f;
    if (p == pp) {  // need Wo'_re (sign +)
        for (int j = 0; j < 64; j++) {
            float hr = Hr[d*64+j], hi = Hi[d*64+j];
            s += hr*Wo_re[(size_t)(h*64+j)*512 + c] - hi*Wo_im[(size_t)(h*64+j)*512 + c];
        }
    } else {        // need Wo'_im; sign - when (p==0,pp==1)
        for (int j = 0; j < 64; j++) {
            float hr = Hr[d*64+j], hi = Hi[d*64+j];
            s += hr*Wo_im[(size_t)(h*64+j)*512 + c] + hi*Wo_re[(size_t)(h*64+j)*512 + c];
        }
        if (p == 0) s = -s;
    }
    Wbig[(size_t)np*1024 + kk] = f2b(s);
}

// ---------------- 5. GEMM: C[M][N] = A[M][K] @ Bt[N][K]^T, bf16 in, fp32 acc ----------------
// 128x128 tile, BK=32, 4 waves each 64x64 (4x4 of 16x16x32 MFMA).
// MODE 0: QKV gemm -> QK buffer (cols<2048) bf16 + Vt transposed (cols>=2048)
// MODE 1: out gemm -> fp32 C[M][1024] (d_out, re/im already column-interleaved)
template<int MODE>
__global__ __launch_bounds__(256, 2) void k_gemm(
        const unsigned short* __restrict__ A, const unsigned short* __restrict__ Bt,
        void* __restrict__ Cout, unsigned short* __restrict__ Vt, int K) {
    __shared__ __align__(16) unsigned short Al[128*32];
    __shared__ __align__(16) unsigned short Bl[128*32];
    const int t = threadIdx.x;
    const int wave = t >> 6, lane = t & 63, quad = lane >> 4, l16 = lane & 15;
    const int wr = wave >> 1, wc = wave & 1;
    const int m0 = blockIdx.x * 128, n0 = blockIdx.y * 128;

    f32x4 acc[4][4] = {};
    for (int kt = 0; kt < K; kt += 32) {
        #pragma unroll
        for (int i = 0; i < 2; i++) {
            int g = t + i*256;               // 512 granules of 16B each for A and B
            int r = g >> 2, gr = g & 3;
            bf16x8 va = *(const bf16x8*)&A [(size_t)(m0 + r)*K + kt + gr*8];
            bf16x8 vb = *(const bf16x8*)&Bt[(size_t)(n0 + r)*K + kt + gr*8];
            *(bf16x8*)&Al[g*8] = va;         // [r][32] row-major
            *(bf16x8*)&Bl[g*8] = vb;
        }
        __syncthreads();
        bf16x8 af[4], bfr[4];
        #pragma unroll
        for (int rt = 0; rt < 4; rt++)
            af[rt] = *(const bf16x8*)&Al[(wr*64 + rt*16 + l16)*32 + quad*8];
        #pragma unroll
        for (int ct = 0; ct < 4; ct++)
            bfr[ct] = *(const bf16x8*)&Bl[(wc*64 + ct*16 + l16)*32 + quad*8];
        #pragma unroll
        for (int rt = 0; rt < 4; rt++)
            #pragma unroll
            for (int ct = 0; ct < 4; ct++)
                acc[rt][ct] = __builtin_amdgcn_mfma_f32_16x16x32_bf16(af[rt], bfr[ct], acc[rt][ct], 0, 0, 0);
        __syncthreads();
    }
    // epilogue: D layout col=lane&15, row=quad*4+reg
    #pragma unroll
    for (int rt = 0; rt < 4; rt++) {
        int row = m0 + wr*64 + rt*16 + quad*4;
        #pragma unroll
        for (int ct = 0; ct < 4; ct++) {
            int col = n0 + wc*64 + ct*16 + l16;
            if (MODE == 0) {
                if (col < 2048) {
                    unsigned short* C = (unsigned short*)Cout;
                    #pragma unroll
                    for (int r = 0; r < 4; r++)
                        C[(size_t)(row + r)*2048 + col] = f2b(acc[rt][ct][r]);
                } else {  // V -> transposed store (d-major) for attention B-operand
                    int hd = col - 2048;
                    int h = hd >> 7, d = hd & 127;
                    int b = row >> 11, s = row & 2047;
                    ushort4 pk;
                    pk.x = f2b(acc[rt][ct][0]); pk.y = f2b(acc[rt][ct][1]);
                    pk.z = f2b(acc[rt][ct][2]); pk.w = f2b(acc[rt][ct][3]);
                    *(ushort4*)&Vt[((size_t)(b*8 + h)*128 + d)*2048 + s] = pk;
                }
            } else {
                float* C = (float*)Cout;
                #pragma unroll
                for (int r = 0; r < 4; r++)
                    C[(size_t)(row + r)*1024 + col] = acc[rt][ct][r];
            }
        }
    }
}

// ---------------- 6. flash attention per (b,h): d=128, QT=128, KT=64 ----------------
// scores already scaled to exp2 domain (QSCALE folded into Qtilde weights).
__global__ __launch_bounds__(256, 1) void k_attn(
        const unsigned short* __restrict__ QK,   // [4096][2048]
        const unsigned short* __restrict__ Vt,   // [16*128][2048]
        unsigned short* __restrict__ O) {        // [4096][1024]
    __shared__ __align__(16) unsigned short smem[24576];  // 48 KB
    unsigned short* Kl = smem;          // [4 ks][64 key][32 d]
    unsigned short* Vl = smem + 8192;   // [2 ks][128 d][32 key]
    unsigned short* Pl = smem + 16384;  // [2 ks][128 q][32 key]

    const int t = threadIdx.x, wave = t >> 6, lane = t & 63, quad = lane >> 4, l16 = lane & 15;
    const int bh = blockIdx.y, b = bh >> 3, h = bh & 7;
    const int tok0 = b*2048 + blockIdx.x*128;

    // stage Q tile [4 ks][128 q][32 d] transiently into smem, preload A-frags
    #pragma unroll
    for (int i = 0; i < 8; i++) {
        int g = t + i*256;
        int ks = g >> 9, q = (g >> 2) & 127, gr = g & 3;
        bf16x8 v = *(const bf16x8*)&QK[(size_t)(tok0 + q)*2048 + h*128 + ks*32 + gr*8];
        *(bf16x8*)&smem[g*8] = v;
    }
    __syncthreads();
    bf16x8 qf[2][4];
    #pragma unroll
    for (int rt = 0; rt < 2; rt++)
        #pragma unroll
        for (int ks = 0; ks < 4; ks++)
            qf[rt][ks] = *(const bf16x8*)&smem[ks*4096 + (wave*32 + rt*16 + l16)*32 + quad*8];
    __syncthreads();

    f32x4 Oacc[2][8] = {};
    float ms[2][4], ls[2][4];
    #pragma unroll
    for (int rt = 0; rt < 2; rt++)
        #pragma unroll
        for (int r = 0; r < 4; r++) { ms[rt][r] = -1e30f; ls[rt][r] = 0.f; }

    for (int kt = 0; kt < 2048; kt += 64) {
        // stage K [4][64][32] and V [2][128][32]
        #pragma unroll
        for (int i = 0; i < 4; i++) {
            int g = t + i*256;
            int ks = g >> 8, key = (g >> 2) & 63, gr = g & 3;
            bf16x8 v = *(const bf16x8*)&QK[(size_t)(b*2048 + kt + key)*2048 + 1024 + h*128 + ks*32 + gr*8];
            *(bf16x8*)&Kl[g*8] = v;
        }
        #pragma unroll
        for (int i = 0; i < 4; i++) {
            int g = t + i*256;
            int ks = g >> 9, d = (g >> 2) & 127, gr = g & 3;
            bf16x8 v = *(const bf16x8*)&Vt[((size_t)(bh*128 + d))*2048 + kt + ks*32 + gr*8];
            *(bf16x8*)&Vl[g*8] = v;
        }
        __syncthreads();
        // S = Qtilde @ K^T  (each wave: 32 q-rows x 64 keys)
        f32x4 S[2][4] = {};
        #pragma unroll
        for (int ks = 0; ks < 4; ks++) {
            bf16x8 kf[4];
            #pragma unroll
            for (int ct = 0; ct < 4; ct++)
                kf[ct] = *(const bf16x8*)&Kl[ks*2048 + (ct*16 + l16)*32 + quad*8];
            #pragma unroll
            for (int rt = 0; rt < 2; rt++)
                #pragma unroll
                for (int ct = 0; ct < 4; ct++)
                    S[rt][ct] = __builtin_amdgcn_mfma_f32_16x16x32_bf16(qf[rt][ks], kf[ct], S[rt][ct], 0, 0, 0);
        }
        // online softmax (exp2 domain); row r lives in quad (row = quad*4+r), cols across 16 lanes x 4 ct
        #pragma unroll
        for (int rt = 0; rt < 2; rt++) {
            #pragma unroll
            for (int r = 0; r < 4; r++) {
                float mx = fmaxf(fmaxf(S[rt][0][r], S[rt][1][r]), fmaxf(S[rt][2][r], S[rt][3][r]));
                #pragma unroll
                for (int m = 1; m < 16; m <<= 1) mx = fmaxf(mx, __shfl_xor(mx, m, 64));
                float mold = ms[rt][r];
                float mnew = fmaxf(mold, mx);
                float alpha = exp2f(mold - mnew);
                float rsum = 0.f;
                #pragma unroll
                for (int ct = 0; ct < 4; ct++) {
                    float p = exp2f(S[rt][ct][r] - mnew);
                    S[rt][ct][r] = p;
                    rsum += p;
                }
                #pragma unroll
                for (int m = 1; m < 16; m <<= 1) rsum += __shfl_xor(rsum, m, 64);
                ls[rt][r] = ls[rt][r] * alpha + rsum;
                ms[rt][r] = mnew;
                #pragma unroll
                for (int dt = 0; dt < 8; dt++) Oacc[rt][dt][r] *= alpha;
            }
        }
        // write P (bf16) to wave-private LDS rows; no barrier needed (same-wave RAW)
        #pragma unroll
        for (int rt = 0; rt < 2; rt++)
            #pragma unroll
            for (int ct = 0; ct < 4; ct++) {
                int ks2 = ct >> 1, kk = (ct & 1)*16 + l16;
                int q = wave*32 + rt*16 + quad*4;
                #pragma unroll
                for (int r = 0; r < 4; r++)
                    Pl[ks2*4096 + (q + r)*32 + kk] = f2b(S[rt][ct][r]);
            }
        // O += P @ V
        #pragma unroll
        for (int ks = 0; ks < 2; ks++) {
            bf16x8 pf[2];
            #pragma unroll
            for (int rt = 0; rt < 2; rt++)
                pf[rt] = *(const bf16x8*)&Pl[ks*4096 + (wave*32 + rt*16 + l16)*32 + quad*8];
            #pragma unroll
            for (int dt = 0; dt < 8; dt++) {
                bf16x8 vf = *(const bf16x8*)&Vl[ks*4096 + (dt*16 + l16)*32 + quad*8];
                #pragma unroll
                for (int rt = 0; rt < 2; rt++)
                    Oacc[rt][dt] = __builtin_amdgcn_mfma_f32_16x16x32_bf16(pf[rt], vf, Oacc[rt][dt], 0, 0, 0);
            }
        }
        __syncthreads();  // protect Kl/Vl before next staging
    }
    // epilogue: O /= l, store bf16 [4096][1024]
    #pragma unroll
    for (int rt = 0; rt < 2; rt++) {
        float rl[4];
        #pragma unroll
        for (int r = 0; r < 4; r++) rl[r] = 1.0f / ls[rt][r];
        int tok = tok0 + wave*32 + rt*16 + quad*4;
        #pragma unroll
        for (int dt = 0; dt < 8; dt++) {
            int col = h*128 + dt*16 + l16;
            #pragma unroll
            for (int r = 0; r < 4; r++)
                O[(size_t)(tok + r)*1024 + col] = f2b(Oacc[rt][dt][r] * rl[r]);
        }
    }
}

extern "C" void kernel_launch(void* const* d_in, const int* in_sizes, int n_in,
                              void* d_out, int out_size, void* d_ws, size_t ws_size,
                              hipStream_t stream) {
    (void)in_sizes; (void)n_in; (void)out_size; (void)ws_size;
    const float* x      = (const float*)d_in[0];
    const float* Wq_re  = (const float*)d_in[1];
    const float* Wq_im  = (const float*)d_in[2];
    const float* Wk_re  = (const float*)d_in[3];
    const float* Wk_im  = (const float*)d_in[4];
    const float* Wv_re  = (const float*)d_in[5];
    const float* Wv_im  = (const float*)d_in[6];
    const float* Wm_re  = (const float*)d_in[7];
    const float* Wm_im  = (const float*)d_in[8];
    const float* Wmi_re = (const float*)d_in[9];
    const float* Wmi_im = (const float*)d_in[10];
    const float* Wo_re  = (const float*)d_in[11];
    const float* Wo_im  = (const float*)d_in[12];

    char* ws = (char*)d_ws;
    unsigned short* xn    = (unsigned short*)(ws);
    unsigned short* WqkvT = (unsigned short*)(ws + (4u << 20));
    unsigned short* Wbig  = (unsigned short*)(ws + (7u << 20));
    float*          GH    = (float*)         (ws + (9u << 20));
    unsigned short* QK    = (unsigned short*)(ws + (10u << 20));
    unsigned short* Vt    = (unsigned short*)(ws + (26u << 20));
    unsigned short* Obuf  = (unsigned short*)(ws + (34u << 20));

    k_norm   <<<dim3(1024), dim3(256), 0, stream>>>(x, xn);
    k_gh     <<<dim3(64),   dim3(256), 0, stream>>>(Wm_re, Wm_im, Wmi_re, Wmi_im, GH);
    k_packqkv<<<dim3(6144), dim3(256), 0, stream>>>(Wq_re, Wq_im, Wk_re, Wk_im, Wv_re, Wv_im, GH, WqkvT);
    k_packwo <<<dim3(4096), dim3(256), 0, stream>>>(Wo_re, Wo_im, GH, Wbig);
    k_gemm<0><<<dim3(32, 24), dim3(256), 0, stream>>>(xn, WqkvT, (void*)QK, Vt, 512);
    k_attn   <<<dim3(16, 16), dim3(256), 0, stream>>>(QK, Vt, Obuf);
    k_gemm<1><<<dim3(32, 8),  dim3(256), 0, stream>>>(Obuf, Wbig, d_out, nullptr, 1024);
}

// Round 2
// 334.266 us; speedup vs baseline: 1.1343x; 1.1343x over previous
//
#include <hip/hip_runtime.h>
#include <hip/hip_bf16.h>
#include <stdint.h>

// QuantumGeometricAttention — algebraic refactor:
//   G = Wm Wm^H folded into Wq (scores inner dim 128 real)
//   H = Wm Wmi  folded into Wo (PV inner dim 128 real)
// norm -> fold weights -> [QKV GEMM + V^T GEMM fused] -> flash attn (fixed-max) -> out GEMM.
// ws: 0 xn bf16[4096][512] | 4MB WqkvT bf16[3072][512] | 7MB Wbig bf16[1024][1024]
//     9MB GH f32[4][64][64] | 10MB QK bf16[4096][2048] | 26MB Vt bf16[2048][2048] | 34MB Obuf bf16[4096][1024]

typedef __attribute__((ext_vector_type(8))) short bf16x8;
typedef __attribute__((ext_vector_type(4))) float f32x4;

#define QSCALE 0.18033688011112042f  /* 64^-0.5 * log2(e) */

__device__ __forceinline__ unsigned short f2b(float f) {
    union { float f; unsigned int u; } v; v.f = f;
    unsigned int r = v.u + 0x7fffu + ((v.u >> 16) & 1u);
    return (unsigned short)(r >> 16);
}

__device__ __forceinline__ unsigned int cvtpk(float a, float b) {
    union { __hip_bfloat162 h; unsigned int u; } v;
    v.h = __float22bfloat162_rn(make_float2(a, b));
    return v.u;
}

// async global->LDS, 16B per lane; LDS dest must be uniform base + lane*16
__device__ __forceinline__ void ld16(void* lds, const void* g) {
    __builtin_amdgcn_global_load_lds(
        (__attribute__((address_space(1))) unsigned int*)(g),
        (__attribute__((address_space(3))) unsigned int*)(lds), 16, 0, 0);
}

// ---------------- 1. row L2-normalize + bf16 cast ----------------
__global__ __launch_bounds__(256) void k_norm(const float* __restrict__ x,
                                              unsigned short* __restrict__ xn) {
    int row  = blockIdx.x * 4 + (threadIdx.x >> 6);
    int lane = threadIdx.x & 63;
    const float4* xr = (const float4*)(x + (size_t)row * 512);
    float4 a = xr[lane], b = xr[lane + 64];
    float s = a.x*a.x + a.y*a.y + a.z*a.z + a.w*a.w
            + b.x*b.x + b.y*b.y + b.z*b.z + b.w*b.w;
    #pragma unroll
    for (int m = 1; m < 64; m <<= 1) s += __shfl_xor(s, m, 64);
    float inv = 1.0f / sqrtf(s);
    ushort4 o;
    o.x = f2b(a.x*inv); o.y = f2b(a.y*inv); o.z = f2b(a.z*inv); o.w = f2b(a.w*inv);
    *(ushort4*)&xn[(size_t)row*512 + lane*4] = o;
    o.x = f2b(b.x*inv); o.y = f2b(b.y*inv); o.z = f2b(b.z*inv); o.w = f2b(b.w*inv);
    *(ushort4*)&xn[(size_t)row*512 + 256 + lane*4] = o;
}

// ---------------- 2. G = Wm Wm^H, H = Wm Wmi ----------------
__global__ __launch_bounds__(256) void k_gh(const float* __restrict__ Wm_re, const float* __restrict__ Wm_im,
                                            const float* __restrict__ Wmi_re, const float* __restrict__ Wmi_im,
                                            float* __restrict__ GH) {
    int id = blockIdx.x * 256 + threadIdx.x;   // 16384
    int mat = id >> 12;
    int a = (id >> 6) & 63, c = id & 63;
    float s = 0.f;
    if (mat < 2) {
        for (int m = 0; m < 256; m++) {
            float ar = Wm_re[a*256+m], ai = Wm_im[a*256+m];
            float br = Wm_re[c*256+m], bi = Wm_im[c*256+m];
            s += (mat == 0) ? (ar*br + ai*bi) : (ai*br - ar*bi);
        }
    } else {
        for (int m = 0; m < 256; m++) {
            float ar = Wm_re[a*256+m], ai = Wm_im[a*256+m];
            float br = Wmi_re[m*64+c], bi = Wmi_im[m*64+c];
            s += (mat == 2) ? (ar*br - ai*bi) : (ar*bi + ai*br);
        }
    }
    GH[id] = s;
}

// ---------------- 3. pack WqkvT [3072][512] bf16 ----------------
__global__ __launch_bounds__(256) void k_packqkv(
        const float* __restrict__ Wq_re, const float* __restrict__ Wq_im,
        const float* __restrict__ Wk_re, const float* __restrict__ Wk_im,
        const float* __restrict__ Wv_re, const float* __restrict__ Wv_im,
        const float* __restrict__ GH, unsigned short* __restrict__ WqkvT) {
    int id = blockIdx.x * 256 + threadIdx.x;
    int n = id >> 9, k = id & 511;
    float val;
    if (n < 1024) {
        int h = n >> 7, part = (n >> 6) & 1, j = n & 63;
        const float* Gr = GH;
        const float* Gi = GH + 4096;
        const float* qr = Wq_re + (size_t)k*512 + h*64;
        const float* qi = Wq_im + (size_t)k*512 + h*64;
        float s = 0.f;
        if (part == 0) { for (int d = 0; d < 64; d++) s += qr[d]*Gr[d*64+j] - qi[d]*Gi[d*64+j]; }
        else           { for (int d = 0; d < 64; d++) s += qr[d]*Gi[d*64+j] + qi[d]*Gr[d*64+j]; }
        val = s * QSCALE;
    } else if (n < 2048) {
        int m = n - 1024; int h = m >> 7, part = (m >> 6) & 1, j = m & 63;
        val = (part ? Wk_im : Wk_re)[(size_t)k*512 + h*64 + j];
    } else {
        int m = n - 2048; int h = m >> 7, part = (m >> 6) & 1, j = m & 63;
        val = (part ? Wv_im : Wv_re)[(size_t)k*512 + h*64 + j];
    }
    WqkvT[id] = f2b(val);
}

// ---------------- 4. pack Wbig [1024][1024] bf16 ----------------
__global__ __launch_bounds__(256) void k_packwo(
        const float* __restrict__ Wo_re, const float* __restrict__ Wo_im,
        const float* __restrict__ GH, unsigned short* __restrict__ Wbig) {
    int id = blockIdx.x * 256 + threadIdx.x;
    int np = id >> 10, kk = id & 1023;
    int c = np >> 1, p = np & 1;
    int h = kk >> 7, pp = (kk >> 6) & 1, d = kk & 63;
    const float* Hr = GH + 2*4096;
    const float* Hi = GH + 3*4096;
    float s = 0.f;
    if (p == pp) {
        for (int j = 0; j < 64; j++) {
            float hr = Hr[d*64+j], hi = Hi[d*64+j];
            s += hr*Wo_re[(size_t)(h*64+j)*512 + c] - hi*Wo_im[(size_t)(h*64+j)*512 + c];
        }
    } else {
        for (int j = 0; j < 64; j++) {
            float hr = Hr[d*64+j], hi = Hi[d*64+j];
            s += hr*Wo_im[(size_t)(h*64+j)*512 + c] + hi*Wo_re[(size_t)(h*64+j)*512 + c];
        }
        if (p == 0) s = -s;
    }
    Wbig[(size_t)np*1024 + kk] = f2b(s);
}

// ---------------- 5. GEMM: C = A @ Bt^T, MT x 128 tile, BK=32, async staging ----------------
// MODE 0 (MT=128): y<16 -> QK (bf16, ld 2048). y>=16 -> V^T GEMM: C=Wv~ @ xn_b^T -> Vt (bf16, ld 2048).
// MODE 1 (MT=64): out gemm -> fp32 C[M][1024] (d_out).
template<int MODE, int MT>
__global__ __launch_bounds__(256, 2) void k_gemm(
        const unsigned short* __restrict__ Ain, const unsigned short* __restrict__ Btin,
        void* __restrict__ Cout, unsigned short* __restrict__ Vt, int K) {
    __shared__ __align__(16) unsigned short Al[MT*32];
    __shared__ __align__(16) unsigned short Bl[128*32];
    const int t = threadIdx.x;
    const int wave = t >> 6, lane = t & 63, quad = lane >> 4, l16 = lane & 15;
    const int wr = wave >> 1, wc = wave & 1;

    const unsigned short* A;
    const unsigned short* Bt;
    unsigned short* Cb = nullptr;
    int m0, n0;
    if (MODE == 0) {
        if (blockIdx.y < 16) {
            A = Ain; Bt = Btin;
            m0 = blockIdx.x * 128; n0 = blockIdx.y * 128;
            Cb = (unsigned short*)Cout;
        } else {
            int idx = (blockIdx.y - 16) * 32 + blockIdx.x;   // [0,256)
            int b = idx >> 7, mt = (idx >> 4) & 7, nt = idx & 15;
            A  = Btin + 2048*512;                 // V rows of WqkvT
            Bt = Ain + (size_t)b*2048*512;        // xn of batch b
            m0 = mt * 128; n0 = nt * 128;
            Cb = Vt + (size_t)b*1024*2048;
        }
    } else {
        A = Ain; Bt = Btin;
        m0 = blockIdx.x * MT; n0 = blockIdx.y * 128;
    }

    f32x4 acc[MT/32][4] = {};
    for (int kt = 0; kt < K; kt += 32) {
        #pragma unroll
        for (int i = 0; i < MT/64; i++) {
            int g = t + i*256, r = g >> 2, gr = g & 3;
            ld16(&Al[g*8], &A[(size_t)(m0 + r)*K + kt + gr*8]);
        }
        #pragma unroll
        for (int i = 0; i < 2; i++) {
            int g = t + i*256, r = g >> 2, gr = g & 3;
            ld16(&Bl[g*8], &Bt[(size_t)(n0 + r)*K + kt + gr*8]);
        }
        __syncthreads();
        bf16x8 af[MT/32], bfr[4];
        #pragma unroll
        for (int rt = 0; rt < MT/32; rt++)
            af[rt] = *(const bf16x8*)&Al[(wr*(MT/2) + rt*16 + l16)*32 + quad*8];
        #pragma unroll
        for (int ct = 0; ct < 4; ct++)
            bfr[ct] = *(const bf16x8*)&Bl[(wc*64 + ct*16 + l16)*32 + quad*8];
        #pragma unroll
        for (int rt = 0; rt < MT/32; rt++)
            #pragma unroll
            for (int ct = 0; ct < 4; ct++)
                acc[rt][ct] = __builtin_amdgcn_mfma_f32_16x16x32_bf16(af[rt], bfr[ct], acc[rt][ct], 0, 0, 0);
        __syncthreads();
    }
    #pragma unroll
    for (int rt = 0; rt < MT/32; rt++) {
        int row = m0 + wr*(MT/2) + rt*16 + quad*4;
        #pragma unroll
        for (int ct = 0; ct < 4; ct++) {
            int col = n0 + wc*64 + ct*16 + l16;
            if (MODE == 0) {
                unsigned int u01 = cvtpk(acc[rt][ct][0], acc[rt][ct][1]);
                unsigned int u23 = cvtpk(acc[rt][ct][2], acc[rt][ct][3]);
                Cb[(size_t)(row+0)*2048 + col] = (unsigned short)(u01);
                Cb[(size_t)(row+1)*2048 + col] = (unsigned short)(u01 >> 16);
                Cb[(size_t)(row+2)*2048 + col] = (unsigned short)(u23);
                Cb[(size_t)(row+3)*2048 + col] = (unsigned short)(u23 >> 16);
            } else {
                float* C = (float*)Cout;
                #pragma unroll
                for (int r = 0; r < 4; r++)
                    C[(size_t)(row + r)*1024 + col] = acc[rt][ct][r];
            }
        }
    }
}

// ---------------- 6. flash attention, fixed-max softmax. QT=64, KT=64, d=128 ----------------
__global__ __launch_bounds__(256, 2) void k_attn(
        const unsigned short* __restrict__ QK,   // [4096][2048]
        const unsigned short* __restrict__ Vt,   // [2048][2048]
        unsigned short* __restrict__ O) {        // [4096][1024]
    __shared__ __align__(16) unsigned short Kl[8192];   // [4ks][64][32] (Q tile staged here first)
    __shared__ __align__(16) unsigned short Vl[8192];   // [2ks2][128 d][32 key]
    __shared__ __align__(16) unsigned short Pl[4608];   // [2ks2][64 q][36]  (stride 36: conflict-free b16 writes)

    const int t = threadIdx.x, wave = t >> 6, lane = t & 63, quad = lane >> 4, l16 = lane & 15;
    const int bh = blockIdx.y, b = bh >> 3, h = bh & 7;
    const int tok0 = b*2048 + blockIdx.x*64;

    // stage Q [4ks][64q][32] via async copy, pull A-frags to regs
    #pragma unroll
    for (int i = 0; i < 4; i++) {
        int g = t + i*256, ks = g >> 8, q = (g >> 2) & 63, gr = g & 3;
        ld16(&Kl[g*8], &QK[(size_t)(tok0 + q)*2048 + h*128 + ks*32 + gr*8]);
    }
    __syncthreads();
    bf16x8 qf[4];
    #pragma unroll
    for (int ks = 0; ks < 4; ks++)
        qf[ks] = *(const bf16x8*)&Kl[ks*2048 + (wave*16 + l16)*32 + quad*8];
    __syncthreads();

    f32x4 Oacc[8] = {};
    float ls[4] = {0.f, 0.f, 0.f, 0.f};

    for (int kt = 0; kt < 2048; kt += 64) {
        #pragma unroll
        for (int i = 0; i < 4; i++) {
            int g = t + i*256, ks = g >> 8, key = (g >> 2) & 63, gr = g & 3;
            ld16(&Kl[g*8], &QK[(size_t)(b*2048 + kt + key)*2048 + 1024 + h*128 + ks*32 + gr*8]);
        }
        #pragma unroll
        for (int i = 0; i < 4; i++) {
            int g = t + i*256, ks2 = g >> 9, d = (g >> 2) & 127, gr = g & 3;
            ld16(&Vl[g*8], &Vt[(size_t)(b*1024 + h*128 + d)*2048 + kt + ks2*32 + gr*8]);
        }
        __syncthreads();

        // S = Q~ @ K^T : wave covers 16 q x 64 keys
        f32x4 S[4] = {};
        #pragma unroll
        for (int ks = 0; ks < 4; ks++) {
            #pragma unroll
            for (int ct = 0; ct < 4; ct++) {
                bf16x8 kf = *(const bf16x8*)&Kl[ks*2048 + (ct*16 + l16)*32 + quad*8];
                S[ct] = __builtin_amdgcn_mfma_f32_16x16x32_bf16(qf[ks], kf, S[ct], 0, 0, 0);
            }
        }
        // fixed-max softmax: p = exp2(s); per-lane denominator accumulation (no cross-lane ops)
        #pragma unroll
        for (int ct = 0; ct < 4; ct++) {
            #pragma unroll
            for (int r = 0; r < 4; r++) {
                float p = exp2f(S[ct][r]);
                S[ct][r] = p;
                ls[r] += p;
            }
            int q = wave*16 + quad*4;
            int base = (ct >> 1)*2304 + (ct & 1)*16 + l16;
            unsigned int u01 = cvtpk(S[ct][0], S[ct][1]);
            unsigned int u23 = cvtpk(S[ct][2], S[ct][3]);
            Pl[base + (q+0)*36] = (unsigned short)(u01);
            Pl[base + (q+1)*36] = (unsigned short)(u01 >> 16);
            Pl[base + (q+2)*36] = (unsigned short)(u23);
            Pl[base + (q+3)*36] = (unsigned short)(u23 >> 16);
        }
        // O += P @ V (wave-private P rows; same-wave RAW, no barrier)
        #pragma unroll
        for (int ks2 = 0; ks2 < 2; ks2++) {
            bf16x8 pf = *(const bf16x8*)&Pl[ks2*2304 + (wave*16 + l16)*36 + quad*8];
            #pragma unroll
            for (int dt = 0; dt < 8; dt++) {
                bf16x8 vf = *(const bf16x8*)&Vl[ks2*4096 + (dt*16 + l16)*32 + quad*8];
                Oacc[dt] = __builtin_amdgcn_mfma_f32_16x16x32_bf16(pf, vf, Oacc[dt], 0, 0, 0);
            }
        }
        __syncthreads();
    }

    // final denominator reduce (within 16-lane col groups) + normalize + store
    #pragma unroll
    for (int r = 0; r < 4; r++) {
        float s = ls[r];
        #pragma unroll
        for (int m = 1; m < 16; m <<= 1) s += __shfl_xor(s, m, 64);
        ls[r] = 1.0f / s;
    }
    int tok = tok0 + wave*16 + quad*4;
    #pragma unroll
    for (int dt = 0; dt < 8; dt++) {
        int col = h*128 + dt*16 + l16;
        unsigned int u01 = cvtpk(Oacc[dt][0]*ls[0], Oacc[dt][1]*ls[1]);
        unsigned int u23 = cvtpk(Oacc[dt][2]*ls[2], Oacc[dt][3]*ls[3]);
        O[(size_t)(tok+0)*1024 + col] = (unsigned short)(u01);
        O[(size_t)(tok+1)*1024 + col] = (unsigned short)(u01 >> 16);
        O[(size_t)(tok+2)*1024 + col] = (unsigned short)(u23);
        O[(size_t)(tok+3)*1024 + col] = (unsigned short)(u23 >> 16);
    }
}

extern "C" void kernel_launch(void* const* d_in, const int* in_sizes, int n_in,
                              void* d_out, int out_size, void* d_ws, size_t ws_size,
                              hipStream_t stream) {
    (void)in_sizes; (void)n_in; (void)out_size; (void)ws_size;
    const float* x      = (const float*)d_in[0];
    const float* Wq_re  = (const float*)d_in[1];
    const float* Wq_im  = (const float*)d_in[2];
    const float* Wk_re  = (const float*)d_in[3];
    const float* Wk_im  = (const float*)d_in[4];
    const float* Wv_re  = (const float*)d_in[5];
    const float* Wv_im  = (const float*)d_in[6];
    const float* Wm_re  = (const float*)d_in[7];
    const float* Wm_im  = (const float*)d_in[8];
    const float* Wmi_re = (const float*)d_in[9];
    const float* Wmi_im = (const float*)d_in[10];
    const float* Wo_re  = (const float*)d_in[11];
    const float* Wo_im  = (const float*)d_in[12];

    char* ws = (char*)d_ws;
    unsigned short* xn    = (unsigned short*)(ws);
    unsigned short* WqkvT = (unsigned short*)(ws + (4u << 20));
    unsigned short* Wbig  = (unsigned short*)(ws + (7u << 20));
    float*          GH    = (float*)         (ws + (9u << 20));
    unsigned short* QK    = (unsigned short*)(ws + (10u << 20));
    unsigned short* Vt    = (unsigned short*)(ws + (26u << 20));
    unsigned short* Obuf  = (unsigned short*)(ws + (34u << 20));

    k_norm      <<<dim3(1024), dim3(256), 0, stream>>>(x, xn);
    k_gh        <<<dim3(64),   dim3(256), 0, stream>>>(Wm_re, Wm_im, Wmi_re, Wmi_im, GH);
    k_packqkv   <<<dim3(6144), dim3(256), 0, stream>>>(Wq_re, Wq_im, Wk_re, Wk_im, Wv_re, Wv_im, GH, WqkvT);
    k_packwo    <<<dim3(4096), dim3(256), 0, stream>>>(Wo_re, Wo_im, GH, Wbig);
    k_gemm<0,128><<<dim3(32, 24), dim3(256), 0, stream>>>(xn, WqkvT, (void*)QK, Vt, 512);
    k_attn      <<<dim3(32, 16), dim3(256), 0, stream>>>(QK, Vt, Obuf);
    k_gemm<1,64> <<<dim3(64, 8), dim3(256), 0, stream>>>(Obuf, Wbig, d_out, nullptr, 1024);
}

// Round 3
// 271.389 us; speedup vs baseline: 1.3972x; 1.2317x over previous
//
#include <hip/hip_runtime.h>
#include <hip/hip_bf16.h>
#include <stdint.h>

// QuantumGeometricAttention — algebraic refactor:
//   G = Wm Wm^H folded into Wq (scores inner dim 128 real)
//   H = Wm Wmi  folded into Wo (PV inner dim 128 real)
// norm -> transpose weights -> fold -> [QKV GEMM + V^T GEMM] -> flash attn (fixed-max) -> out GEMM.
// ws: 0 xn bf16[4096][512] | 4MB WqkvT bf16[3072][512] | 7MB Wbig bf16[1024][1024]
//     9MB GH f32[4][64][64] (H parts stored TRANSPOSED) | 9MB+64K WmT_re | 9MB+128K WmT_im
//     10MB QK bf16[4096][2048]  (transient: W*T fp32 transposes live here before gemm0 overwrites)
//     26MB Vt bf16[2048][2048] | 34MB Obuf bf16[4096][1024]

typedef __attribute__((ext_vector_type(8))) short bf16x8;
typedef __attribute__((ext_vector_type(4))) float f32x4;

#define QSCALE 0.18033688011112042f  /* 64^-0.5 * log2(e) */

__device__ __forceinline__ unsigned short f2b(float f) {
    union { float f; unsigned int u; } v; v.f = f;
    unsigned int r = v.u + 0x7fffu + ((v.u >> 16) & 1u);
    return (unsigned short)(r >> 16);
}

__device__ __forceinline__ unsigned int cvtpk(float a, float b) {
    union { __hip_bfloat162 h; unsigned int u; } v;
    v.h = __float22bfloat162_rn(make_float2(a, b));
    return v.u;
}

__device__ __forceinline__ void ld16(void* lds, const void* g) {
    __builtin_amdgcn_global_load_lds(
        (__attribute__((address_space(1))) unsigned int*)(g),
        (__attribute__((address_space(3))) unsigned int*)(lds), 16, 0, 0);
}

// ---------------- 1. row L2-normalize + bf16 cast ----------------
__global__ __launch_bounds__(256) void k_norm(const float* __restrict__ x,
                                              unsigned short* __restrict__ xn) {
    int row  = blockIdx.x * 4 + (threadIdx.x >> 6);
    int lane = threadIdx.x & 63;
    const float4* xr = (const float4*)(x + (size_t)row * 512);
    float4 a = xr[lane], b = xr[lane + 64];
    float s = a.x*a.x + a.y*a.y + a.z*a.z + a.w*a.w
            + b.x*b.x + b.y*b.y + b.z*b.z + b.w*b.w;
    #pragma unroll
    for (int m = 1; m < 64; m <<= 1) s += __shfl_xor(s, m, 64);
    float inv = 1.0f / sqrtf(s);
    ushort4 o;
    o.x = f2b(a.x*inv); o.y = f2b(a.y*inv); o.z = f2b(a.z*inv); o.w = f2b(a.w*inv);
    *(ushort4*)&xn[(size_t)row*512 + lane*4] = o;
    o.x = f2b(b.x*inv); o.y = f2b(b.y*inv); o.z = f2b(b.z*inv); o.w = f2b(b.w*inv);
    *(ushort4*)&xn[(size_t)row*512 + 256 + lane*4] = o;
}

// ---------------- 1b. tiled fp32 transpose (all 8 weight matrices in one launch) ----------------
// blocks 0..383: six 512x512 mats (64 tiles each); 384..391: two 64x256 mats (4 tiles each)
__global__ __launch_bounds__(256) void k_trans(
        const float* __restrict__ s0, const float* __restrict__ s1,
        const float* __restrict__ s2, const float* __restrict__ s3,
        const float* __restrict__ s4, const float* __restrict__ s5,
        const float* __restrict__ s6, const float* __restrict__ s7,
        float* __restrict__ d0, float* __restrict__ d1,
        float* __restrict__ d2, float* __restrict__ d3,
        float* __restrict__ d4, float* __restrict__ d5,
        float* __restrict__ d6, float* __restrict__ d7) {
    __shared__ float tile[64][65];
    int bid = blockIdx.x;
    const float* src; float* dst; int R, C, tr, tc;
    if (bid < 384) {
        int mat = bid >> 6, tl = bid & 63;
        src = (mat==0)?s0:(mat==1)?s1:(mat==2)?s2:(mat==3)?s3:(mat==4)?s4:s5;
        dst = (mat==0)?d0:(mat==1)?d1:(mat==2)?d2:(mat==3)?d3:(mat==4)?d4:d5;
        R = 512; C = 512; tr = tl >> 3; tc = tl & 7;
    } else {
        int mat = (bid - 384) >> 2, tl = (bid - 384) & 3;
        src = mat ? s7 : s6; dst = mat ? d7 : d6;
        R = 64; C = 256; tr = 0; tc = tl;
    }
    int r0 = tr * 64, c0 = tc * 64;
    int tx = threadIdx.x & 63, ty = threadIdx.x >> 6;
    #pragma unroll
    for (int i = 0; i < 16; i++) {
        int r = ty + i*4;
        tile[r][tx] = src[(size_t)(r0 + r)*C + c0 + tx];
    }
    __syncthreads();
    #pragma unroll
    for (int i = 0; i < 16; i++) {
        int r = ty + i*4;
        dst[(size_t)(c0 + r)*R + r0 + tx] = tile[tx][r];
    }
}

// ---------------- 2. G = Wm Wm^H (row-major), Ht = (Wm Wmi)^T ----------------
__global__ __launch_bounds__(256) void k_gh(const float* __restrict__ Wm_re, const float* __restrict__ Wm_im,
                                            const float* __restrict__ WmT_re, const float* __restrict__ WmT_im,
                                            const float* __restrict__ Wmi_re, const float* __restrict__ Wmi_im,
                                            float* __restrict__ GH) {
    int id = blockIdx.x * 256 + threadIdx.x;   // 16384
    int mat = id >> 12;
    int a = (id >> 6) & 63, c = id & 63;       // a wave-uniform, c = lane
    float s = 0.f;
    if (mat < 2) {
        for (int m = 0; m < 256; m++) {
            float ar = Wm_re[a*256+m], ai = Wm_im[a*256+m];   // broadcast
            float br = WmT_re[m*64+c], bi = WmT_im[m*64+c];   // lane-contiguous
            s += (mat == 0) ? (ar*br + ai*bi) : (ai*br - ar*bi);
        }
        GH[id] = s;
    } else {
        for (int m = 0; m < 256; m++) {
            float ar = Wm_re[a*256+m], ai = Wm_im[a*256+m];   // broadcast
            float br = Wmi_re[m*64+c], bi = Wmi_im[m*64+c];   // lane-contiguous
            s += (mat == 2) ? (ar*br - ai*bi) : (ar*bi + ai*br);
        }
        GH[mat*4096 + c*64 + a] = s;   // store H TRANSPOSED (HT[j][d] = H[d][j])
    }
}

// ---------------- 3. pack WqkvT [3072][512] bf16 (reads from transposed weights) ----------------
__global__ __launch_bounds__(256) void k_packqkv(
        const float* __restrict__ WqT_re, const float* __restrict__ WqT_im,
        const float* __restrict__ WkT_re, const float* __restrict__ WkT_im,
        const float* __restrict__ WvT_re, const float* __restrict__ WvT_im,
        const float* __restrict__ GH, unsigned short* __restrict__ WqkvT) {
    int id = blockIdx.x * 256 + threadIdx.x;
    int n = id >> 9, k = id & 511;             // n wave-uniform, k = lane
    float val;
    if (n < 1024) {
        int h = n >> 7, part = (n >> 6) & 1, j = n & 63;
        const float* Gr = GH;
        const float* Gi = GH + 4096;
        const float* qr = WqT_re + (size_t)(h*64)*512 + k;
        const float* qi = WqT_im + (size_t)(h*64)*512 + k;
        float s = 0.f;
        if (part == 0) { for (int d = 0; d < 64; d++) s += qr[d*512]*Gr[d*64+j] - qi[d*512]*Gi[d*64+j]; }
        else           { for (int d = 0; d < 64; d++) s += qr[d*512]*Gi[d*64+j] + qi[d*512]*Gr[d*64+j]; }
        val = s * QSCALE;
    } else if (n < 2048) {
        int m = n - 1024; int h = m >> 7, part = (m >> 6) & 1, j = m & 63;
        val = (part ? WkT_im : WkT_re)[(size_t)(h*64+j)*512 + k];
    } else {
        int m = n - 2048; int h = m >> 7, part = (m >> 6) & 1, j = m & 63;
        val = (part ? WvT_im : WvT_re)[(size_t)(h*64+j)*512 + k];
    }
    WqkvT[id] = f2b(val);
}

// ---------------- 4. pack Wbig [1024][1024] bf16 (H reads lane-contiguous via HT) ----------------
__global__ __launch_bounds__(256) void k_packwo(
        const float* __restrict__ Wo_re, const float* __restrict__ Wo_im,
        const float* __restrict__ GH, unsigned short* __restrict__ Wbig) {
    int id = blockIdx.x * 256 + threadIdx.x;
    int np = id >> 10, kk = id & 1023;         // np wave-uniform, lanes vary d
    int c = np >> 1, p = np & 1;
    int h = kk >> 7, pp = (kk >> 6) & 1, d = kk & 63;
    const float* HrT = GH + 2*4096;
    const float* HiT = GH + 3*4096;
    float s = 0.f;
    if (p == pp) {
        for (int j = 0; j < 64; j++) {
            float hr = HrT[j*64+d], hi = HiT[j*64+d];                      // lane-contiguous
            float wr = Wo_re[(size_t)(h*64+j)*512 + c];                    // broadcast
            float wi = Wo_im[(size_t)(h*64+j)*512 + c];
            s += hr*wr - hi*wi;
        }
    } else {
        for (int j = 0; j < 64; j++) {
            float hr = HrT[j*64+d], hi = HiT[j*64+d];
            float wr = Wo_re[(size_t)(h*64+j)*512 + c];
            float wi = Wo_im[(size_t)(h*64+j)*512 + c];
            s += hr*wi + hi*wr;
        }
        if (p == 0) s = -s;
    }
    Wbig[(size_t)np*1024 + kk] = f2b(s);
}

// ---------------- 5. GEMM: C = A @ Bt^T, MT x 128 tile, BK=32, async staging ----------------
template<int MODE, int MT>
__global__ __launch_bounds__(256, 2) void k_gemm(
        const unsigned short* __restrict__ Ain, const unsigned short* __restrict__ Btin,
        void* __restrict__ Cout, unsigned short* __restrict__ Vt, int K) {
    __shared__ __align__(16) unsigned short Al[MT*32];
    __shared__ __align__(16) unsigned short Bl[128*32];
    const int t = threadIdx.x;
    const int wave = t >> 6, lane = t & 63, quad = lane >> 4, l16 = lane & 15;
    const int wr = wave >> 1, wc = wave & 1;

    const unsigned short* A;
    const unsigned short* Bt;
    unsigned short* Cb = nullptr;
    int m0, n0;
    if (MODE == 0) {
        if (blockIdx.y < 16) {
            A = Ain; Bt = Btin;
            m0 = blockIdx.x * 128; n0 = blockIdx.y * 128;
            Cb = (unsigned short*)Cout;
        } else {
            int idx = (blockIdx.y - 16) * 32 + blockIdx.x;
            int b = idx >> 7, mt = (idx >> 4) & 7, nt = idx & 15;
            A  = Btin + 2048*512;
            Bt = Ain + (size_t)b*2048*512;
            m0 = mt * 128; n0 = nt * 128;
            Cb = Vt + (size_t)b*1024*2048;
        }
    } else {
        A = Ain; Bt = Btin;
        m0 = blockIdx.x * MT; n0 = blockIdx.y * 128;
    }

    f32x4 acc[MT/32][4] = {};
    for (int kt = 0; kt < K; kt += 32) {
        #pragma unroll
        for (int i = 0; i < MT/64; i++) {
            int g = t + i*256, r = g >> 2, gr = g & 3;
            ld16(&Al[g*8], &A[(size_t)(m0 + r)*K + kt + gr*8]);
        }
        #pragma unroll
        for (int i = 0; i < 2; i++) {
            int g = t + i*256, r = g >> 2, gr = g & 3;
            ld16(&Bl[g*8], &Bt[(size_t)(n0 + r)*K + kt + gr*8]);
        }
        __syncthreads();
        bf16x8 af[MT/32], bfr[4];
        #pragma unroll
        for (int rt = 0; rt < MT/32; rt++)
            af[rt] = *(const bf16x8*)&Al[(wr*(MT/2) + rt*16 + l16)*32 + quad*8];
        #pragma unroll
        for (int ct = 0; ct < 4; ct++)
            bfr[ct] = *(const bf16x8*)&Bl[(wc*64 + ct*16 + l16)*32 + quad*8];
        #pragma unroll
        for (int rt = 0; rt < MT/32; rt++)
            #pragma unroll
            for (int ct = 0; ct < 4; ct++)
                acc[rt][ct] = __builtin_amdgcn_mfma_f32_16x16x32_bf16(af[rt], bfr[ct], acc[rt][ct], 0, 0, 0);
        __syncthreads();
    }
    #pragma unroll
    for (int rt = 0; rt < MT/32; rt++) {
        int row = m0 + wr*(MT/2) + rt*16 + quad*4;
        #pragma unroll
        for (int ct = 0; ct < 4; ct++) {
            int col = n0 + wc*64 + ct*16 + l16;
            if (MODE == 0) {
                unsigned int u01 = cvtpk(acc[rt][ct][0], acc[rt][ct][1]);
                unsigned int u23 = cvtpk(acc[rt][ct][2], acc[rt][ct][3]);
                Cb[(size_t)(row+0)*2048 + col] = (unsigned short)(u01);
                Cb[(size_t)(row+1)*2048 + col] = (unsigned short)(u01 >> 16);
                Cb[(size_t)(row+2)*2048 + col] = (unsigned short)(u23);
                Cb[(size_t)(row+3)*2048 + col] = (unsigned short)(u23 >> 16);
            } else {
                float* C = (float*)Cout;
                #pragma unroll
                for (int r = 0; r < 4; r++)
                    C[(size_t)(row + r)*1024 + col] = acc[rt][ct][r];
            }
        }
    }
}

// ---------------- 6. flash attention, fixed-max softmax. QT=64, KT=64, d=128 ----------------
__global__ __launch_bounds__(256, 2) void k_attn(
        const unsigned short* __restrict__ QK,   // [4096][2048]
        const unsigned short* __restrict__ Vt,   // [2048][2048]
        unsigned short* __restrict__ O) {        // [4096][1024]
    __shared__ __align__(16) unsigned short Kl[8192];   // [4ks][64][32]
    __shared__ __align__(16) unsigned short Vl[8192];   // [2ks2][128 d][32 key]
    __shared__ __align__(16) unsigned short Pl[4608];   // [2ks2][64 q][36]

    const int t = threadIdx.x, wave = t >> 6, lane = t & 63, quad = lane >> 4, l16 = lane & 15;
    const int bh = blockIdx.y, b = bh >> 3, h = bh & 7;
    const int tok0 = b*2048 + blockIdx.x*64;

    #pragma unroll
    for (int i = 0; i < 4; i++) {
        int g = t + i*256, ks = g >> 8, q = (g >> 2) & 63, gr = g & 3;
        ld16(&Kl[g*8], &QK[(size_t)(tok0 + q)*2048 + h*128 + ks*32 + gr*8]);
    }
    __syncthreads();
    bf16x8 qf[4];
    #pragma unroll
    for (int ks = 0; ks < 4; ks++)
        qf[ks] = *(const bf16x8*)&Kl[ks*2048 + (wave*16 + l16)*32 + quad*8];
    __syncthreads();

    f32x4 Oacc[8] = {};
    float ls[4] = {0.f, 0.f, 0.f, 0.f};

    for (int kt = 0; kt < 2048; kt += 64) {
        #pragma unroll
        for (int i = 0; i < 4; i++) {
            int g = t + i*256, ks = g >> 8, key = (g >> 2) & 63, gr = g & 3;
            ld16(&Kl[g*8], &QK[(size_t)(b*2048 + kt + key)*2048 + 1024 + h*128 + ks*32 + gr*8]);
        }
        #pragma unroll
        for (int i = 0; i < 4; i++) {
            int g = t + i*256, ks2 = g >> 9, d = (g >> 2) & 127, gr = g & 3;
            ld16(&Vl[g*8], &Vt[(size_t)(b*1024 + h*128 + d)*2048 + kt + ks2*32 + gr*8]);
        }
        __syncthreads();

        f32x4 S[4] = {};
        #pragma unroll
        for (int ks = 0; ks < 4; ks++) {
            #pragma unroll
            for (int ct = 0; ct < 4; ct++) {
                bf16x8 kf = *(const bf16x8*)&Kl[ks*2048 + (ct*16 + l16)*32 + quad*8];
                S[ct] = __builtin_amdgcn_mfma_f32_16x16x32_bf16(qf[ks], kf, S[ct], 0, 0, 0);
            }
        }
        #pragma unroll
        for (int ct = 0; ct < 4; ct++) {
            #pragma unroll
            for (int r = 0; r < 4; r++) {
                float p = exp2f(S[ct][r]);
                S[ct][r] = p;
                ls[r] += p;
            }
            int q = wave*16 + quad*4;
            int base = (ct >> 1)*2304 + (ct & 1)*16 + l16;
            unsigned int u01 = cvtpk(S[ct][0], S[ct][1]);
            unsigned int u23 = cvtpk(S[ct][2], S[ct][3]);
            Pl[base + (q+0)*36] = (unsigned short)(u01);
            Pl[base + (q+1)*36] = (unsigned short)(u01 >> 16);
            Pl[base + (q+2)*36] = (unsigned short)(u23);
            Pl[base + (q+3)*36] = (unsigned short)(u23 >> 16);
        }
        #pragma unroll
        for (int ks2 = 0; ks2 < 2; ks2++) {
            bf16x8 pf = *(const bf16x8*)&Pl[ks2*2304 + (wave*16 + l16)*36 + quad*8];
            #pragma unroll
            for (int dt = 0; dt < 8; dt++) {
                bf16x8 vf = *(const bf16x8*)&Vl[ks2*4096 + (dt*16 + l16)*32 + quad*8];
                Oacc[dt] = __builtin_amdgcn_mfma_f32_16x16x32_bf16(pf, vf, Oacc[dt], 0, 0, 0);
            }
        }
        __syncthreads();
    }

    #pragma unroll
    for (int r = 0; r < 4; r++) {
        float s = ls[r];
        #pragma unroll
        for (int m = 1; m < 16; m <<= 1) s += __shfl_xor(s, m, 64);
        ls[r] = 1.0f / s;
    }
    int tok = tok0 + wave*16 + quad*4;
    #pragma unroll
    for (int dt = 0; dt < 8; dt++) {
        int col = h*128 + dt*16 + l16;
        unsigned int u01 = cvtpk(Oacc[dt][0]*ls[0], Oacc[dt][1]*ls[1]);
        unsigned int u23 = cvtpk(Oacc[dt][2]*ls[2], Oacc[dt][3]*ls[3]);
        O[(size_t)(tok+0)*1024 + col] = (unsigned short)(u01);
        O[(size_t)(tok+1)*1024 + col] = (unsigned short)(u01 >> 16);
        O[(size_t)(tok+2)*1024 + col] = (unsigned short)(u23);
        O[(size_t)(tok+3)*1024 + col] = (unsigned short)(u23 >> 16);
    }
}

extern "C" void kernel_launch(void* const* d_in, const int* in_sizes, int n_in,
                              void* d_out, int out_size, void* d_ws, size_t ws_size,
                              hipStream_t stream) {
    (void)in_sizes; (void)n_in; (void)out_size; (void)ws_size;
    const float* x      = (const float*)d_in[0];
    const float* Wq_re  = (const float*)d_in[1];
    const float* Wq_im  = (const float*)d_in[2];
    const float* Wk_re  = (const float*)d_in[3];
    const float* Wk_im  = (const float*)d_in[4];
    const float* Wv_re  = (const float*)d_in[5];
    const float* Wv_im  = (const float*)d_in[6];
    const float* Wm_re  = (const float*)d_in[7];
    const float* Wm_im  = (const float*)d_in[8];
    const float* Wmi_re = (const float*)d_in[9];
    const float* Wmi_im = (const float*)d_in[10];
    const float* Wo_re  = (const float*)d_in[11];
    const float* Wo_im  = (const float*)d_in[12];

    char* ws = (char*)d_ws;
    unsigned short* xn    = (unsigned short*)(ws);
    unsigned short* WqkvT = (unsigned short*)(ws + (4u << 20));
    unsigned short* Wbig  = (unsigned short*)(ws + (7u << 20));
    float*          GH    = (float*)         (ws + (9u << 20));
    float*          WmT_re= (float*)         (ws + (9u << 20) + (64u << 10));
    float*          WmT_im= (float*)         (ws + (9u << 20) + (128u << 10));
    unsigned short* QK    = (unsigned short*)(ws + (10u << 20));
    unsigned short* Vt    = (unsigned short*)(ws + (26u << 20));
    unsigned short* Obuf  = (unsigned short*)(ws + (34u << 20));
    // transient fp32 transposes inside QK's region (overwritten by gemm0 later)
    float* WqT_re = (float*)(ws + (10u << 20));
    float* WqT_im = (float*)(ws + (11u << 20));
    float* WkT_re = (float*)(ws + (12u << 20));
    float* WkT_im = (float*)(ws + (13u << 20));
    float* WvT_re = (float*)(ws + (14u << 20));
    float* WvT_im = (float*)(ws + (15u << 20));

    k_norm      <<<dim3(1024), dim3(256), 0, stream>>>(x, xn);
    k_trans     <<<dim3(392),  dim3(256), 0, stream>>>(
        Wq_re, Wq_im, Wk_re, Wk_im, Wv_re, Wv_im, Wm_re, Wm_im,
        WqT_re, WqT_im, WkT_re, WkT_im, WvT_re, WvT_im, WmT_re, WmT_im);
    k_gh        <<<dim3(64),   dim3(256), 0, stream>>>(Wm_re, Wm_im, WmT_re, WmT_im, Wmi_re, Wmi_im, GH);
    k_packqkv   <<<dim3(6144), dim3(256), 0, stream>>>(WqT_re, WqT_im, WkT_re, WkT_im, WvT_re, WvT_im, GH, WqkvT);
    k_packwo    <<<dim3(4096), dim3(256), 0, stream>>>(Wo_re, Wo_im, GH, Wbig);
    k_gemm<0,128><<<dim3(32, 24), dim3(256), 0, stream>>>(xn, WqkvT, (void*)QK, Vt, 512);
    k_attn      <<<dim3(32, 16), dim3(256), 0, stream>>>(QK, Vt, Obuf);
    k_gemm<1,64> <<<dim3(64, 8), dim3(256), 0, stream>>>(Obuf, Wbig, d_out, nullptr, 1024);
}